// Round 5
// baseline (2964.343 us; speedup 1.0000x reference)
//
#include <hip/hip_runtime.h>
#include <hip/hip_bf16.h>
#include <stdint.h>

// a3c_lstm_ga forward, MI355X. Float tensors f32 (bf16-rounded values), ints
// int32. Output f32: [critic(1), actor(4), hx_new(768), cx_new(768)].
// Bug-faithful: only attn[0] consumed -> one GRU scan.
//
// R11: B-frags pinned in AGPRs. R10 counters: FETCH_SIZE 3.3GB/dispatch and
// VGPR_Count=124 < the 192 regs the 48 B-frags need -> the "+v" launder
// outside the loop did NOT pin lifetimes; the compiler rematerialized the
// W_hh fragment loads from global memory EVERY step (48 global_load_dwordx4
// per wave per step, ~0.8GB+ total) and the MFMA stream stalled on vmcnt.
// Fix: B-frags are u32x4 (native 128-bit vectors -> contiguous reg quads),
// laundered with "+a" (AGPR class) INSIDE the scan loop -> loop-carried
// through AGPRs, cannot be remat'd as loads. gfx950 MFMA reads B directly
// from AGPRs (AVSrc operands), so steady state has zero copies. Budget:
// 192 AGPR + ~60 VGPR <= 256 keeps 2 waves/SIMD.
// Epilogue (R10): lanes with (n16&3)==1 read the LO plane for A, so every
// quad's D regs .x/.y = hi/lo of its column; lane l<32 owns element
// 32w+(l&31) and runs ONE gate chain. First-chunk MFMAs use C=zero4.
// h enters MFMA as A rows: hi rows = h_hi (f16), lo rows = (h-h_hi)*1024;
// y = hi + lo/1024.

typedef _Float16 half8 __attribute__((ext_vector_type(8)));
typedef _Float16 half2v __attribute__((ext_vector_type(2)));
typedef float f32x4 __attribute__((ext_vector_type(4)));
typedef uint32_t u32x4 __attribute__((ext_vector_type(4)));

__device__ __forceinline__ float sigm(float x) { return 1.0f / (1.0f + __expf(-x)); }
__device__ __forceinline__ float tanh_f(float x) { return 2.0f / (1.0f + __expf(-2.0f * x)) - 1.0f; }

// ---------------- pack W_hh f32 -> f16 pairs ----------------
__global__ void k_pack(const float* __restrict__ whh, uint32_t* __restrict__ wf16p) {
    int i = blockIdx.x * 256 + threadIdx.x;  // 98304 pairs
    if (i >= 98304) return;
    half2v p = {(_Float16)whh[2 * i], (_Float16)whh[2 * i + 1]};
    wf16p[i] = __builtin_bit_cast(uint32_t, p);
}

// ---------------- conv tower ----------------
__global__ void k_conv1(const float* __restrict__ x, const float* __restrict__ w,
                        const float* __restrict__ b, float* __restrict__ h1) {
    int idx = blockIdx.x * 256 + threadIdx.x;
    if (idx >= 128 * 30 * 30) return;
    int ox = idx % 30, oy = (idx / 30) % 30, oc = idx / 900;
    const float* wr = w + oc * 192;
    float acc = b[oc];
    for (int c = 0; c < 3; ++c)
        for (int ky = 0; ky < 8; ++ky) {
            const float* xr = x + (c * 124 + oy * 4 + ky) * 124 + ox * 4;
            const float* wk = wr + (c * 8 + ky) * 8;
#pragma unroll
            for (int kx = 0; kx < 8; ++kx) acc = fmaf(xr[kx], wk[kx], acc);
        }
    h1[idx] = fmaxf(acc, 0.0f);
}

__global__ void k_conv2(const float* __restrict__ h1, const float* __restrict__ w,
                        const float* __restrict__ b, float* __restrict__ h2) {
    int idx = blockIdx.x * 256 + threadIdx.x;
    if (idx >= 64 * 14 * 14) return;
    int ox = idx % 14, oy = (idx / 14) % 14, oc = idx / 196;
    float acc = b[oc];
    const float* wr = w + oc * 128 * 16;
    for (int c = 0; c < 128; ++c) {
#pragma unroll
        for (int ky = 0; ky < 4; ++ky) {
            const float* hr = h1 + (c * 30 + oy * 2 + ky) * 30 + ox * 2;
            const float* wk = wr + (c * 4 + ky) * 4;
#pragma unroll
            for (int kx = 0; kx < 4; ++kx) acc = fmaf(hr[kx], wk[kx], acc);
        }
    }
    h2[idx] = fmaxf(acc, 0.0f);
}

__global__ void k_conv3(const float* __restrict__ h2, const float* __restrict__ w,
                        const float* __restrict__ b, float* __restrict__ x3) {
    int idx = blockIdx.x * 256 + threadIdx.x;
    if (idx >= 64 * 6 * 6) return;
    int ox = idx % 6, oy = (idx / 6) % 6, oc = idx / 36;
    float acc = b[oc];
    const float* wr = w + oc * 64 * 16;
    for (int c = 0; c < 64; ++c) {
#pragma unroll
        for (int ky = 0; ky < 4; ++ky) {
            const float* hr = h2 + (c * 14 + oy * 2 + ky) * 14 + ox * 2;
            const float* wk = wr + (c * 4 + ky) * 4;
#pragma unroll
            for (int kx = 0; kx < 4; ++kx) acc = fmaf(hr[kx], wk[kx], acc);
        }
    }
    x3[idx] = fmaxf(acc, 0.0f);
}

// ---------------- GRU input-gate precompute (b_hh folded for r,z rows) ----------------
__global__ void k_gi(const int* __restrict__ curr, const float* __restrict__ emb,
                     const float* __restrict__ wih, const float* __restrict__ bih,
                     const float* __restrict__ bhh, float* __restrict__ gi) {
    int idx = blockIdx.x * 256 + threadIdx.x;  // 2048*768
    int j = idx % 768, t = idx / 768;
    int tok = curr[t];
    const float4* e = (const float4*)(emb + tok * 32);
    const float4* wr = (const float4*)(wih + j * 32);
    float acc = bih[j] + (j < 512 ? bhh[j] : 0.0f);
#pragma unroll
    for (int k = 0; k < 8; ++k) {
        float4 ev = e[k], wv = wr[k];
        acc = fmaf(ev.x, wv.x, acc);
        acc = fmaf(ev.y, wv.y, acc);
        acc = fmaf(ev.z, wv.z, acc);
        acc = fmaf(ev.w, wv.w, acc);
    }
    gi[idx] = acc;
}

// ---------------- MFMA GRU scan: 512 thr, 8 waves, 2 waves/SIMD ----------------
#define FOR8(X, nt) X(nt, 0) X(nt, 1) X(nt, 2) X(nt, 3) X(nt, 4) X(nt, 5) X(nt, 6) X(nt, 7)
#define FOR6(Y) Y(0) Y(1) Y(2) Y(3) Y(4) Y(5)

#define DECLB(nt, kt) u32x4 b##nt##_##kt;
#define DECLBROW(nt) FOR8(DECLB, nt)
#define LOADB(nt, kt) b##nt##_##kt = wp##nt[kt * 4 + quad];
#define LOADBROW(nt) \
    { const u32x4* wp##nt = wb4 + (size_t)(TB##nt + n16) * 32; FOR8(LOADB, nt) }
// AGPR pin: "+a" inside the loop makes the value loop-carried in an AGPR quad
// (contiguous 128-bit tuple); compiler cannot remat it as a global load.
#define TIEB(nt, kt) asm volatile("" : "+a"(b##nt##_##kt));
#define TIEBROW(nt) FOR8(TIEB, nt)
#define DECLACC(nt) f32x4 acc##nt;
#define MF(nt, kt) \
    acc##nt = __builtin_amdgcn_mfma_f32_16x16x32_f16(a##kt, __builtin_bit_cast(half8, b##nt##_##kt), acc##nt, 0, 0, 0);
// chunk-0 MFMA uses C = zero4 (no per-step acc zero-init)
#define MFZ(nt) \
    acc##nt = __builtin_amdgcn_mfma_f32_16x16x32_f16(a0, __builtin_bit_cast(half8, b##nt##_0), zero4, 0, 0, 0);
// order R0,R1,N0,N1,Z0,Z1: r finishes first (feeds tanh), z consumed last
#define MFK0 MFZ(0) MFZ(1) MFZ(4) MFZ(5) MFZ(2) MFZ(3)
#define MFK(kt) MF(0, kt) MF(1, kt) MF(4, kt) MF(5, kt) MF(2, kt) MF(3, kt)
#define LOADA(kt) half8 a##kt = __builtin_bit_cast(half8, abIN[kt * 4 + quad]);

#define SC 0.0009765625f

// One GRU step: read h from hbuf[PIN], write h to hbuf[POUT]. Single barrier.
// Lanes 0-31 each own one element eL = 32*wv + (lane&31): hi=acc.x, lo=acc.y
// valid in every quad (lo-plane A rows 1,5,9,13).
#define GRU_BODY(PIN, POUT)                                                       \
    {                                                                             \
        float gvR = 0.f, gvZ = 0.f, gvN = 0.f;                                    \
        if (lane < 32) { gvR = gpL[0]; gvZ = gpL[256]; gvN = gpL[512]; }          \
        gpL += 768;                                                               \
        const uint4* abIN = hb##PIN;                                              \
        LOADA(0) LOADA(1)                                                         \
        MFK0                                                                      \
        LOADA(2)                                                                  \
        MFK(1)                                                                    \
        LOADA(3)                                                                  \
        MFK(2)                                                                    \
        LOADA(4)                                                                  \
        MFK(3)                                                                    \
        LOADA(5)                                                                  \
        MFK(4)                                                                    \
        LOADA(6)                                                                  \
        MFK(5)                                                                    \
        LOADA(7)                                                                  \
        MFK(6)                                                                    \
        MFK(7)                                                                    \
        if (lane < 32) {                                                          \
            bool hi16 = (lane & 16) != 0;                                         \
            float hR = hi16 ? acc1.x : acc0.x;                                    \
            float lR = hi16 ? acc1.y : acc0.y;                                    \
            float hZ = hi16 ? acc3.x : acc2.x;                                    \
            float lZ = hi16 ? acc3.y : acc2.y;                                    \
            float hN = hi16 ? acc5.x : acc4.x;                                    \
            float lN = hi16 ? acc5.y : acc4.y;                                    \
            float yR = fmaf(lR, SC, hR) + gvR;                                    \
            float yZ = fmaf(lZ, SC, hZ) + gvZ;                                    \
            float yN = fmaf(lN, SC, hN) + bNL;                                    \
            float r = sigm(yR), z = sigm(yZ);                                     \
            float n = tanh_f(fmaf(r, yN, gvN));                                   \
            h_own = fmaf(z, h_own - n, n);                                        \
            _Float16 hh = (_Float16)h_own;                                        \
            hbuf[POUT][0][eL] = hh;                                               \
            hbuf[POUT][1][eL] = (_Float16)((h_own - (float)hh) * 1024.0f);        \
        }                                                                         \
        __syncthreads();                                                          \
    }

__global__ __attribute__((amdgpu_flat_work_group_size(512, 512), amdgpu_waves_per_eu(2, 2)))
void k_gru_scan(const float* __restrict__ gi, const uint32_t* __restrict__ wf16p,
                const float* __restrict__ bhh, const float* __restrict__ attn_w,
                const float* __restrict__ attn_b, float* __restrict__ attn0) {
    // h double-buffer: [parity][hi/lo][256] f16
    __shared__ __align__(16) _Float16 hbuf[2][2][256];
    const int tid = threadIdx.x;   // 0..511
    const int lane = tid & 63;
    const int wv = tid >> 6;       // wave 0..7
    const int n16 = lane & 15;     // B col (output row-in-tile); also A row m
    const int quad = lane >> 4;    // k-subchunk selector

    // wave w owns elements [32w, 32w+32): rows r: [32w,..), z: 256+, n: 512+
    const int TB0 = 32 * wv, TB1 = TB0 + 16;
    const int TB2 = 256 + TB0, TB3 = 256 + TB1;
    const int TB4 = 512 + TB0, TB5 = 512 + TB1;
    const int eL = TB0 + (lane & 31);  // element owned by lanes 0-31

    // B-frags: lane holds W[TBt + n16][kt*32 + quad*8 + j], j=0..7
    FOR6(DECLBROW)
    {
        const u32x4* wb4 = (const u32x4*)wf16p;
        FOR6(LOADBROW)
    }
    FOR6(DECLACC)
    const f32x4 zero4 = (f32x4)(0.0f);

    // n-gate bias (r,z biases folded into gi by k_gi)
    const float bNL = bhh[512 + eL];

    float h_own = 0.0f;  // lane<32: owns h[eL]
    if (tid < 256) {
        hbuf[0][0][tid] = (_Float16)0.0f;
        hbuf[0][1][tid] = (_Float16)0.0f;
    }
    // A-frag base: lanes with (n16&3)==1 read the LO plane -> A rows 1,5,9,13
    // = lo, so every quad's D regs .x/.y = hi/lo of its column.
    const bool loLane = ((n16 & 3) == 1);
    const uint4* hb0 = (const uint4*)(loLane ? hbuf[0][1] : hbuf[0][0]);
    const uint4* hb1 = (const uint4*)(loLane ? hbuf[1][1] : hbuf[1][0]);

    __syncthreads();

    const float* gpL = gi + eL;  // advanced +768 per step inside GRU_BODY

#pragma clang loop unroll(disable)
    for (int it = 0; it < 1024; ++it) {
        FOR6(TIEBROW)  // AGPR-pin the 48 B-frags; loop-carried, no remat
        GRU_BODY(0, 1)
        GRU_BODY(1, 0)
    }
    // 2048 steps done; final h in hbuf[0]

    // fused attention head: attn0[j] = sigm(attn_w[j] . h + attn_b[j]), j<64
    if (tid < 64) {
        const float* ar = attn_w + tid * 256;
        float acc = attn_b[tid];
        for (int k = 0; k < 256; ++k) {
            float hk = (float)hbuf[0][0][k] + (float)hbuf[0][1][k] * SC;
            acc = fmaf(ar[k], hk, acc);
        }
        attn0[tid] = sigm(acc);
    }
}

// ---------------- fuse + linear ----------------
__global__ void k_feat(const float* __restrict__ x3, const float* __restrict__ attn0,
                       const float* __restrict__ lw, const float* __restrict__ lb,
                       float* __restrict__ feat) {
    __shared__ __align__(16) float fused[2304];
    int t = threadIdx.x;  // 64
    for (int i = t; i < 2304; i += 64) fused[i] = x3[i] * attn0[i / 36];
    __syncthreads();
    int row = blockIdx.x * 64 + t;
    const float4* wvv = (const float4*)(lw + (size_t)row * 2304);
    float acc = lb[row];
    for (int i = 0; i < 576; ++i) {
        float4 v = wvv[i];
        const float* f = fused + i * 4;
        acc = fmaf(v.x, f[0], acc);
        acc = fmaf(v.y, f[1], acc);
        acc = fmaf(v.z, f[2], acc);
        acc = fmaf(v.w, f[3], acc);
    }
    feat[row] = fmaxf(acc, 0.0f);
}

// ---------------- LSTM gates ----------------
__global__ void k_lstm_gates(const float* __restrict__ wih, const float* __restrict__ whh,
                             const float* __restrict__ bih, const float* __restrict__ bhh,
                             const float* __restrict__ hx, const float* __restrict__ feat,
                             float* __restrict__ gates) {
    int wid = threadIdx.x >> 6, lane = threadIdx.x & 63;
    int row = blockIdx.x * 4 + wid;
    const float* wi = wih + (size_t)row * 768;
    const float* wh = whh + (size_t)row * 768;
    float acc = 0.0f;
#pragma unroll
    for (int i = 0; i < 12; ++i) {
        int k = lane + i * 64;
        acc = fmaf(wi[k], feat[k & 255], acc);
        acc = fmaf(wh[k], hx[k], acc);
    }
#pragma unroll
    for (int s = 32; s; s >>= 1) acc += __shfl_down(acc, s, 64);
    if (lane == 0) gates[row] = acc + bih[row] + bhh[row];
}

// ---------------- LSTM cell ----------------
__global__ void k_lstm_cell(const float* __restrict__ gates, const float* __restrict__ cx,
                            float* __restrict__ out, float* __restrict__ hxf) {
    int i = threadIdx.x;  // 768
    float g_i = gates[i], g_f = gates[768 + i], g_g = gates[1536 + i], g_o = gates[2304 + i];
    float c = cx[i];
    float cn = sigm(g_f) * c + sigm(g_i) * tanh_f(g_g);
    float hn = sigm(g_o) * tanh_f(cn);
    out[5 + i] = hn;
    out[5 + 768 + i] = cn;
    hxf[i] = hn;
}

// ---------------- heads ----------------
__global__ void k_heads(const float* __restrict__ hxf, const float* __restrict__ temb,
                        const int* __restrict__ tx, const float* __restrict__ cw,
                        const float* __restrict__ cb, const float* __restrict__ aw,
                        const float* __restrict__ ab, float* __restrict__ out) {
    __shared__ float z[800];
    int t = threadIdx.x;  // 320
    for (int i = t; i < 768; i += 320) z[i] = hxf[i];
    if (t < 32) z[768 + t] = temb[tx[0] * 32 + t];
    __syncthreads();
    int w = t >> 6, lane = t & 63;
    const float* row = (w == 0) ? cw : (aw + (size_t)(w - 1) * 800);
    float acc = 0.0f;
    for (int k = lane; k < 800; k += 64) acc = fmaf(row[k], z[k], acc);
#pragma unroll
    for (int s = 32; s; s >>= 1) acc += __shfl_down(acc, s, 64);
    if (lane == 0) {
        float b = (w == 0) ? cb[0] : ab[w - 1];
        out[w] = acc + b;
    }
}

extern "C" void kernel_launch(void* const* d_in, const int* in_sizes, int n_in,
                              void* d_out, int out_size, void* d_ws, size_t ws_size,
                              hipStream_t stream) {
    const float* x = (const float*)d_in[0];
    const int* curr = (const int*)d_in[1];
    const int* tx = (const int*)d_in[4];
    const float* hx = (const float*)d_in[5];
    const float* cx = (const float*)d_in[6];
    const float* c1w = (const float*)d_in[7];
    const float* c1b = (const float*)d_in[8];
    const float* c2w = (const float*)d_in[9];
    const float* c2b = (const float*)d_in[10];
    const float* c3w = (const float*)d_in[11];
    const float* c3b = (const float*)d_in[12];
    const float* emb = (const float*)d_in[13];
    const float* temb = (const float*)d_in[14];
    const float* gwih = (const float*)d_in[15];
    const float* gwhh = (const float*)d_in[16];
    const float* gbih = (const float*)d_in[17];
    const float* gbhh = (const float*)d_in[18];
    const float* attw = (const float*)d_in[19];
    const float* attb = (const float*)d_in[20];
    const float* linw = (const float*)d_in[21];
    const float* linb = (const float*)d_in[22];
    const float* lwih = (const float*)d_in[23];
    const float* lwhh = (const float*)d_in[24];
    const float* lbih = (const float*)d_in[25];
    const float* lbhh = (const float*)d_in[26];
    const float* cw = (const float*)d_in[27];
    const float* cb = (const float*)d_in[28];
    const float* aw = (const float*)d_in[29];
    const float* ab = (const float*)d_in[30];
    float* out = (float*)d_out;

    char* ws = (char*)d_ws;
    float* gi = (float*)(ws + 0);                 // 2048*768 f32
    float* h1 = (float*)(ws + 6291456);
    float* h2 = (float*)(ws + 6752256);
    float* x3 = (float*)(ws + 6802432);
    float* attn0 = (float*)(ws + 6811648);
    float* feat = (float*)(ws + 6811904);
    float* gates = (float*)(ws + 6812928);
    float* hxf = (float*)(ws + 6825216);
    uint32_t* wf16p = (uint32_t*)(ws + 6828288);  // 98304 u32 (f16-pair W_hh)

    k_pack<<<384, 256, 0, stream>>>(gwhh, wf16p);
    k_gi<<<6144, 256, 0, stream>>>(curr, emb, gwih, gbih, gbhh, gi);
    k_conv1<<<450, 256, 0, stream>>>(x, c1w, c1b, h1);
    k_conv2<<<49, 256, 0, stream>>>(h1, c2w, c2b, h2);
    k_conv3<<<9, 256, 0, stream>>>(h2, c3w, c3b, x3);
    k_gru_scan<<<1, 512, 0, stream>>>(gi, wf16p, gbhh, attw, attb, attn0);
    k_feat<<<4, 64, 0, stream>>>(x3, attn0, linw, linb, feat);
    k_lstm_gates<<<768, 256, 0, stream>>>(lwih, lwhh, lbih, lbhh, hx, feat, gates);
    k_lstm_cell<<<1, 768, 0, stream>>>(gates, cx, out, hxf);
    k_heads<<<1, 320, 0, stream>>>(hxf, temb, tx, cw, cb, aw, ab, out);
}

// Round 6
// 2295.110 us; speedup vs baseline: 1.2916x; 1.2916x over previous
//
#include <hip/hip_runtime.h>
#include <hip/hip_bf16.h>
#include <stdint.h>

// a3c_lstm_ga forward, MI355X. Float tensors f32 (bf16-rounded values), ints
// int32. Output f32: [critic(1), actor(4), hx_new(768), cx_new(768)].
// Bug-faithful: only attn[0] consumed -> one GRU scan.
//
// R12: scan reverted EXACTLY to R10 (best measured: 2016us, MfmaUtil 0.252).
// R11 post-mortem: FETCH_SIZE is KB (3.3MB, = gi stream -- no W remat ever
// existed); VGPR_Count excludes AGPRs, so R10's B-frags were already fully
// register-resident (124 VGPR + ~128 AGPR = 252/wave x 2 waves = 504 <= 512
// per SIMD). R11's in-loop "+a" launder just added accvgpr copies (VALUBusy
// 0.162->0.274). Barrier-region pipelining attempts (R8, R9) both regressed;
// not re-rolled. R12 only trims launch overhead: k_pack folded into k_gi's
// grid; k_lstm_cell+k_heads fused. 10 -> 8 dispatches.
//
// Scan structure (R10): 512 thr / 8 waves / 2 waves per SIMD. Wave w owns the
// r,z,n rows of elements [32w,32w+32). Lanes with (n16&3)==1 read the LO
// plane for A, so A rows 1,5,9,13 = lo and EVERY quad's D regs .x/.y = hi/lo
// of its column. Lane l<32 owns element 32w+(l&31) and runs ONE gate chain.
// First-chunk MFMAs use C=zero4. MFMA order R,R,N,N,Z,Z (r feeds tanh).
// h enters MFMA as A rows: hi rows = h_hi (f16), lo rows = (h-h_hi)*1024;
// y = hi + lo/1024 (dodges f16 subnormals).

typedef _Float16 half8 __attribute__((ext_vector_type(8)));
typedef _Float16 half2v __attribute__((ext_vector_type(2)));
typedef float f32x4 __attribute__((ext_vector_type(4)));

__device__ __forceinline__ float sigm(float x) { return 1.0f / (1.0f + __expf(-x)); }
__device__ __forceinline__ float tanh_f(float x) { return 2.0f / (1.0f + __expf(-2.0f * x)) - 1.0f; }

// ---------------- conv tower ----------------
__global__ void k_conv1(const float* __restrict__ x, const float* __restrict__ w,
                        const float* __restrict__ b, float* __restrict__ h1) {
    int idx = blockIdx.x * 256 + threadIdx.x;
    if (idx >= 128 * 30 * 30) return;
    int ox = idx % 30, oy = (idx / 30) % 30, oc = idx / 900;
    const float* wr = w + oc * 192;
    float acc = b[oc];
    for (int c = 0; c < 3; ++c)
        for (int ky = 0; ky < 8; ++ky) {
            const float* xr = x + (c * 124 + oy * 4 + ky) * 124 + ox * 4;
            const float* wk = wr + (c * 8 + ky) * 8;
#pragma unroll
            for (int kx = 0; kx < 8; ++kx) acc = fmaf(xr[kx], wk[kx], acc);
        }
    h1[idx] = fmaxf(acc, 0.0f);
}

__global__ void k_conv2(const float* __restrict__ h1, const float* __restrict__ w,
                        const float* __restrict__ b, float* __restrict__ h2) {
    int idx = blockIdx.x * 256 + threadIdx.x;
    if (idx >= 64 * 14 * 14) return;
    int ox = idx % 14, oy = (idx / 14) % 14, oc = idx / 196;
    float acc = b[oc];
    const float* wr = w + oc * 128 * 16;
    for (int c = 0; c < 128; ++c) {
#pragma unroll
        for (int ky = 0; ky < 4; ++ky) {
            const float* hr = h1 + (c * 30 + oy * 2 + ky) * 30 + ox * 2;
            const float* wk = wr + (c * 4 + ky) * 4;
#pragma unroll
            for (int kx = 0; kx < 4; ++kx) acc = fmaf(hr[kx], wk[kx], acc);
        }
    }
    h2[idx] = fmaxf(acc, 0.0f);
}

__global__ void k_conv3(const float* __restrict__ h2, const float* __restrict__ w,
                        const float* __restrict__ b, float* __restrict__ x3) {
    int idx = blockIdx.x * 256 + threadIdx.x;
    if (idx >= 64 * 6 * 6) return;
    int ox = idx % 6, oy = (idx / 6) % 6, oc = idx / 36;
    float acc = b[oc];
    const float* wr = w + oc * 64 * 16;
    for (int c = 0; c < 64; ++c) {
#pragma unroll
        for (int ky = 0; ky < 4; ++ky) {
            const float* hr = h2 + (c * 14 + oy * 2 + ky) * 14 + ox * 2;
            const float* wk = wr + (c * 4 + ky) * 4;
#pragma unroll
            for (int kx = 0; kx < 4; ++kx) acc = fmaf(hr[kx], wk[kx], acc);
        }
    }
    x3[idx] = fmaxf(acc, 0.0f);
}

// ---------------- GRU input-gate precompute (b_hh folded for r,z rows)
// + W_hh f32->f16-pair pack folded in as extra grid blocks ----------------
__global__ void k_gi(const int* __restrict__ curr, const float* __restrict__ emb,
                     const float* __restrict__ wih, const float* __restrict__ bih,
                     const float* __restrict__ bhh, const float* __restrict__ whh,
                     uint32_t* __restrict__ wf16p, float* __restrict__ gi) {
    if (blockIdx.x >= 6144) {  // pack branch: 384 blocks, 98304 f16 pairs
        int i = (blockIdx.x - 6144) * 256 + threadIdx.x;
        if (i < 98304) {
            half2v p = {(_Float16)whh[2 * i], (_Float16)whh[2 * i + 1]};
            wf16p[i] = __builtin_bit_cast(uint32_t, p);
        }
        return;
    }
    int idx = blockIdx.x * 256 + threadIdx.x;  // 2048*768
    int j = idx % 768, t = idx / 768;
    int tok = curr[t];
    const float4* e = (const float4*)(emb + tok * 32);
    const float4* wr = (const float4*)(wih + j * 32);
    float acc = bih[j] + (j < 512 ? bhh[j] : 0.0f);
#pragma unroll
    for (int k = 0; k < 8; ++k) {
        float4 ev = e[k], wv = wr[k];
        acc = fmaf(ev.x, wv.x, acc);
        acc = fmaf(ev.y, wv.y, acc);
        acc = fmaf(ev.z, wv.z, acc);
        acc = fmaf(ev.w, wv.w, acc);
    }
    gi[idx] = acc;
}

// ---------------- MFMA GRU scan: 512 thr, 8 waves, 2 waves/SIMD ----------------
#define FOR8(X, nt) X(nt, 0) X(nt, 1) X(nt, 2) X(nt, 3) X(nt, 4) X(nt, 5) X(nt, 6) X(nt, 7)
#define FOR6(Y) Y(0) Y(1) Y(2) Y(3) Y(4) Y(5)

#define DECLB(nt, kt) uint4 b##nt##_##kt;
#define DECLBROW(nt) FOR8(DECLB, nt)
#define LOADB(nt, kt) b##nt##_##kt = wp##nt[kt * 4 + quad];
#define LOADBROW(nt) \
    { const uint4* wp##nt = wb4 + (size_t)(TB##nt + n16) * 32; FOR8(LOADB, nt) }
#define TIEB(nt, kt) \
    asm volatile("" : "+v"(b##nt##_##kt.x), "+v"(b##nt##_##kt.y), "+v"(b##nt##_##kt.z), "+v"(b##nt##_##kt.w));
#define TIEBROW(nt) FOR8(TIEB, nt)
#define DECLACC(nt) f32x4 acc##nt;
#define MF(nt, kt) \
    acc##nt = __builtin_amdgcn_mfma_f32_16x16x32_f16(a##kt, __builtin_bit_cast(half8, b##nt##_##kt), acc##nt, 0, 0, 0);
// chunk-0 MFMA uses C = zero4 (no per-step acc zero-init)
#define MFZ(nt) \
    acc##nt = __builtin_amdgcn_mfma_f32_16x16x32_f16(a0, __builtin_bit_cast(half8, b##nt##_0), zero4, 0, 0, 0);
// order R0,R1,N0,N1,Z0,Z1: r finishes first (feeds tanh), z consumed last
#define MFK0 MFZ(0) MFZ(1) MFZ(4) MFZ(5) MFZ(2) MFZ(3)
#define MFK(kt) MF(0, kt) MF(1, kt) MF(4, kt) MF(5, kt) MF(2, kt) MF(3, kt)
#define LOADA(kt) half8 a##kt = __builtin_bit_cast(half8, abIN[kt * 4 + quad]);

#define SC 0.0009765625f

// One GRU step: read h from hbuf[PIN], write h to hbuf[POUT]. Single barrier.
// Lanes 0-31 each own one element eL = 32*wv + (lane&31): hi=acc.x, lo=acc.y
// valid in every quad (lo-plane A rows 1,5,9,13).
#define GRU_BODY(PIN, POUT)                                                       \
    {                                                                             \
        float gvR = 0.f, gvZ = 0.f, gvN = 0.f;                                    \
        if (lane < 32) { gvR = gpL[0]; gvZ = gpL[256]; gvN = gpL[512]; }          \
        gpL += 768;                                                               \
        const uint4* abIN = hb##PIN;                                              \
        LOADA(0) LOADA(1)                                                         \
        MFK0                                                                      \
        LOADA(2)                                                                  \
        MFK(1)                                                                    \
        LOADA(3)                                                                  \
        MFK(2)                                                                    \
        LOADA(4)                                                                  \
        MFK(3)                                                                    \
        LOADA(5)                                                                  \
        MFK(4)                                                                    \
        LOADA(6)                                                                  \
        MFK(5)                                                                    \
        LOADA(7)                                                                  \
        MFK(6)                                                                    \
        MFK(7)                                                                    \
        if (lane < 32) {                                                          \
            bool hi16 = (lane & 16) != 0;                                         \
            float hR = hi16 ? acc1.x : acc0.x;                                    \
            float lR = hi16 ? acc1.y : acc0.y;                                    \
            float hZ = hi16 ? acc3.x : acc2.x;                                    \
            float lZ = hi16 ? acc3.y : acc2.y;                                    \
            float hN = hi16 ? acc5.x : acc4.x;                                    \
            float lN = hi16 ? acc5.y : acc4.y;                                    \
            float yR = fmaf(lR, SC, hR) + gvR;                                    \
            float yZ = fmaf(lZ, SC, hZ) + gvZ;                                    \
            float yN = fmaf(lN, SC, hN) + bNL;                                    \
            float r = sigm(yR), z = sigm(yZ);                                     \
            float n = tanh_f(fmaf(r, yN, gvN));                                   \
            h_own = fmaf(z, h_own - n, n);                                        \
            _Float16 hh = (_Float16)h_own;                                        \
            hbuf[POUT][0][eL] = hh;                                               \
            hbuf[POUT][1][eL] = (_Float16)((h_own - (float)hh) * 1024.0f);        \
        }                                                                         \
        __syncthreads();                                                          \
    }

__global__ __attribute__((amdgpu_flat_work_group_size(512, 512), amdgpu_waves_per_eu(2, 2)))
void k_gru_scan(const float* __restrict__ gi, const uint32_t* __restrict__ wf16p,
                const float* __restrict__ bhh, const float* __restrict__ attn_w,
                const float* __restrict__ attn_b, float* __restrict__ attn0) {
    // h double-buffer: [parity][hi/lo][256] f16
    __shared__ __align__(16) _Float16 hbuf[2][2][256];
    const int tid = threadIdx.x;   // 0..511
    const int lane = tid & 63;
    const int wv = tid >> 6;       // wave 0..7
    const int n16 = lane & 15;     // B col (output row-in-tile); also A row m
    const int quad = lane >> 4;    // k-subchunk selector

    // wave w owns elements [32w, 32w+32): rows r: [32w,..), z: 256+, n: 512+
    const int TB0 = 32 * wv, TB1 = TB0 + 16;
    const int TB2 = 256 + TB0, TB3 = 256 + TB1;
    const int TB4 = 512 + TB0, TB5 = 512 + TB1;
    const int eL = TB0 + (lane & 31);  // element owned by lanes 0-31

    // B-frags: lane holds W[TBt + n16][kt*32 + quad*8 + j], j=0..7
    FOR6(DECLBROW)
    {
        const uint4* wb4 = (const uint4*)wf16p;
        FOR6(LOADBROW)
    }
    FOR6(TIEBROW)  // launder: cannot be rematerialized by re-loading
    FOR6(DECLACC)
    const f32x4 zero4 = (f32x4)(0.0f);

    // n-gate bias (r,z biases folded into gi by k_gi)
    const float bNL = bhh[512 + eL];

    float h_own = 0.0f;  // lane<32: owns h[eL]
    if (tid < 256) {
        hbuf[0][0][tid] = (_Float16)0.0f;
        hbuf[0][1][tid] = (_Float16)0.0f;
    }
    // A-frag base: lanes with (n16&3)==1 read the LO plane -> A rows 1,5,9,13
    // = lo, so every quad's D regs .x/.y = hi/lo of its column.
    const bool loLane = ((n16 & 3) == 1);
    const uint4* hb0 = (const uint4*)(loLane ? hbuf[0][1] : hbuf[0][0]);
    const uint4* hb1 = (const uint4*)(loLane ? hbuf[1][1] : hbuf[1][0]);

    __syncthreads();

    const float* gpL = gi + eL;  // advanced +768 per step inside GRU_BODY

#pragma clang loop unroll(disable)
    for (int it = 0; it < 1024; ++it) {
        GRU_BODY(0, 1)
        GRU_BODY(1, 0)
    }
    // 2048 steps done; final h in hbuf[0]

    // fused attention head: attn0[j] = sigm(attn_w[j] . h + attn_b[j]), j<64
    if (tid < 64) {
        const float* ar = attn_w + tid * 256;
        float acc = attn_b[tid];
        for (int k = 0; k < 256; ++k) {
            float hk = (float)hbuf[0][0][k] + (float)hbuf[0][1][k] * SC;
            acc = fmaf(ar[k], hk, acc);
        }
        attn0[tid] = sigm(acc);
    }
}

// ---------------- fuse + linear ----------------
__global__ void k_feat(const float* __restrict__ x3, const float* __restrict__ attn0,
                       const float* __restrict__ lw, const float* __restrict__ lb,
                       float* __restrict__ feat) {
    __shared__ __align__(16) float fused[2304];
    int t = threadIdx.x;  // 64
    for (int i = t; i < 2304; i += 64) fused[i] = x3[i] * attn0[i / 36];
    __syncthreads();
    int row = blockIdx.x * 64 + t;
    const float4* wvv = (const float4*)(lw + (size_t)row * 2304);
    float acc = lb[row];
    for (int i = 0; i < 576; ++i) {
        float4 v = wvv[i];
        const float* f = fused + i * 4;
        acc = fmaf(v.x, f[0], acc);
        acc = fmaf(v.y, f[1], acc);
        acc = fmaf(v.z, f[2], acc);
        acc = fmaf(v.w, f[3], acc);
    }
    feat[row] = fmaxf(acc, 0.0f);
}

// ---------------- LSTM gates ----------------
__global__ void k_lstm_gates(const float* __restrict__ wih, const float* __restrict__ whh,
                             const float* __restrict__ bih, const float* __restrict__ bhh,
                             const float* __restrict__ hx, const float* __restrict__ feat,
                             float* __restrict__ gates) {
    int wid = threadIdx.x >> 6, lane = threadIdx.x & 63;
    int row = blockIdx.x * 4 + wid;
    const float* wi = wih + (size_t)row * 768;
    const float* wh = whh + (size_t)row * 768;
    float acc = 0.0f;
#pragma unroll
    for (int i = 0; i < 12; ++i) {
        int k = lane + i * 64;
        acc = fmaf(wi[k], feat[k & 255], acc);
        acc = fmaf(wh[k], hx[k], acc);
    }
#pragma unroll
    for (int s = 32; s; s >>= 1) acc += __shfl_down(acc, s, 64);
    if (lane == 0) gates[row] = acc + bih[row] + bhh[row];
}

// ---------------- LSTM cell + heads (fused; cell feeds heads via LDS) ----------------
__global__ void k_lstm_tail(const float* __restrict__ gates, const float* __restrict__ cx,
                            const float* __restrict__ temb, const int* __restrict__ tx,
                            const float* __restrict__ cw, const float* __restrict__ cb,
                            const float* __restrict__ aw, const float* __restrict__ ab,
                            float* __restrict__ out) {
    __shared__ float z[800];
    int i = threadIdx.x;  // 768
    float g_i = gates[i], g_f = gates[768 + i], g_g = gates[1536 + i], g_o = gates[2304 + i];
    float c = cx[i];
    float cn = sigm(g_f) * c + sigm(g_i) * tanh_f(g_g);
    float hn = sigm(g_o) * tanh_f(cn);
    out[5 + i] = hn;
    out[5 + 768 + i] = cn;
    z[i] = hn;
    if (i < 32) z[768 + i] = temb[tx[0] * 32 + i];
    __syncthreads();
    if (i < 320) {
        int w = i >> 6, lane = i & 63;
        const float* row = (w == 0) ? cw : (aw + (size_t)(w - 1) * 800);
        float acc = 0.0f;
        for (int k = lane; k < 800; k += 64) acc = fmaf(row[k], z[k], acc);
#pragma unroll
        for (int s = 32; s; s >>= 1) acc += __shfl_down(acc, s, 64);
        if (lane == 0) {
            float b = (w == 0) ? cb[0] : ab[w - 1];
            out[w] = acc + b;
        }
    }
}

extern "C" void kernel_launch(void* const* d_in, const int* in_sizes, int n_in,
                              void* d_out, int out_size, void* d_ws, size_t ws_size,
                              hipStream_t stream) {
    const float* x = (const float*)d_in[0];
    const int* curr = (const int*)d_in[1];
    const int* tx = (const int*)d_in[4];
    const float* hx = (const float*)d_in[5];
    const float* cx = (const float*)d_in[6];
    const float* c1w = (const float*)d_in[7];
    const float* c1b = (const float*)d_in[8];
    const float* c2w = (const float*)d_in[9];
    const float* c2b = (const float*)d_in[10];
    const float* c3w = (const float*)d_in[11];
    const float* c3b = (const float*)d_in[12];
    const float* emb = (const float*)d_in[13];
    const float* temb = (const float*)d_in[14];
    const float* gwih = (const float*)d_in[15];
    const float* gwhh = (const float*)d_in[16];
    const float* gbih = (const float*)d_in[17];
    const float* gbhh = (const float*)d_in[18];
    const float* attw = (const float*)d_in[19];
    const float* attb = (const float*)d_in[20];
    const float* linw = (const float*)d_in[21];
    const float* linb = (const float*)d_in[22];
    const float* lwih = (const float*)d_in[23];
    const float* lwhh = (const float*)d_in[24];
    const float* lbih = (const float*)d_in[25];
    const float* lbhh = (const float*)d_in[26];
    const float* cw = (const float*)d_in[27];
    const float* cb = (const float*)d_in[28];
    const float* aw = (const float*)d_in[29];
    const float* ab = (const float*)d_in[30];
    float* out = (float*)d_out;

    char* ws = (char*)d_ws;
    float* gi = (float*)(ws + 0);                 // 2048*768 f32
    float* h1 = (float*)(ws + 6291456);
    float* h2 = (float*)(ws + 6752256);
    float* x3 = (float*)(ws + 6802432);
    float* attn0 = (float*)(ws + 6811648);
    float* feat = (float*)(ws + 6811904);
    float* gates = (float*)(ws + 6812928);
    uint32_t* wf16p = (uint32_t*)(ws + 6828288);  // 98304 u32 (f16-pair W_hh)

    k_gi<<<6528, 256, 0, stream>>>(curr, emb, gwih, gbih, gbhh, gwhh, wf16p, gi);
    k_conv1<<<450, 256, 0, stream>>>(x, c1w, c1b, h1);
    k_conv2<<<49, 256, 0, stream>>>(h1, c2w, c2b, h2);
    k_conv3<<<9, 256, 0, stream>>>(h2, c3w, c3b, x3);
    k_gru_scan<<<1, 512, 0, stream>>>(gi, wf16p, gbhh, attw, attb, attn0);
    k_feat<<<4, 64, 0, stream>>>(x3, attn0, linw, linb, feat);
    k_lstm_gates<<<768, 256, 0, stream>>>(lwih, lwhh, lbih, lbhh, hx, feat, gates);
    k_lstm_tail<<<1, 768, 0, stream>>>(gates, cx, temb, tx, cw, cb, aw, ab, out);
}